// Round 11
// baseline (197.999 us; speedup 1.0000x reference)
//
#include <hip/hip_runtime.h>
#include <hip/hip_bf16.h>
#include <stdint.h>
#include <stddef.h>

// ---------------------------------------------------------------------------
// CausalAttention: x[2,2048,1024] f32, W_QKV[3072,1024], W_O[1024,1024]
// qkv = x @ W_QKV^T ; per-head causal attention ; out = att @ W_O^T
// GEMMs: 128x128 tile, DOUBLE-BUFFERED global_load_lds staging (m97 ladder).
// Attention: R8-measured config — 128-row q-tiles, swapped 32x32 QK^T,
// in-register softmax (exp2), 2-chunk split-KV + f32 partial merge.
// ---------------------------------------------------------------------------

typedef __attribute__((ext_vector_type(8)))  __bf16   bf16x8;
typedef __attribute__((ext_vector_type(4)))  float    f32x4;
typedef __attribute__((ext_vector_type(16))) float    f32x16;
typedef __attribute__((ext_vector_type(4)))  uint32_t u32x4;

#define AS1(p) ((__attribute__((address_space(1))) void*)(p))
#define AS3(p) ((__attribute__((address_space(3))) void*)(p))

static constexpr int Tq    = 2048;
static constexpr int Cd    = 1024;
static constexpr int Mrows = 2 * Tq;   // 4096

// Q pre-scale: 1/sqrt(64) * log2(e)  (softmax runs in exp2 domain)
#define QSCALE 0.18033688011112042f

// ---------------------------------------------------------------------------
// f32 -> bf16 cast, vectorized 8/thread
// ---------------------------------------------------------------------------
__global__ __launch_bounds__(256) void cvt_bf16_kernel(const float* __restrict__ in,
                                                       __bf16* __restrict__ out, int n8)
{
    int idx    = blockIdx.x * blockDim.x + threadIdx.x;
    int stride = gridDim.x * blockDim.x;
    for (int i = idx; i < n8; i += stride) {
        f32x4 a = ((const f32x4*)in)[i * 2 + 0];
        f32x4 b = ((const f32x4*)in)[i * 2 + 1];
        bf16x8 o;
#pragma unroll
        for (int j = 0; j < 4; ++j) { o[j] = (__bf16)a[j]; o[4 + j] = (__bf16)b[j]; }
        ((bf16x8*)out)[i] = o;
    }
}

// ---------------------------------------------------------------------------
// V transpose: qkv V-part (cols 2048..3071) -> vT[1024][4096]
// ---------------------------------------------------------------------------
__global__ __launch_bounds__(256) void transpose_v_kernel(const __bf16* __restrict__ qkv,
                                                          __bf16* __restrict__ vT)
{
    __shared__ __bf16 tile[64][65];
    const int t   = threadIdx.x;
    const int r0  = blockIdx.x * 64;
    const int hd0 = blockIdx.y * 64;

    {
        const int rr = t >> 2, c16 = (t & 3) * 16;
        const __bf16* src = qkv + (size_t)(r0 + rr) * 3072 + 2048 + hd0 + c16;
        bf16x8 a = *(const bf16x8*)(src);
        bf16x8 b = *(const bf16x8*)(src + 8);
#pragma unroll
        for (int j = 0; j < 8; ++j) { tile[rr][c16 + j] = a[j]; tile[rr][c16 + 8 + j] = b[j]; }
    }
    __syncthreads();
    {
        const int hd_loc = t >> 2, rg = (t & 3) * 16;
        bf16x8 a, b;
#pragma unroll
        for (int j = 0; j < 8; ++j) { a[j] = tile[rg + j][hd_loc]; b[j] = tile[rg + 8 + j][hd_loc]; }
        __bf16* dst = vT + (size_t)(hd0 + hd_loc) * Mrows + r0 + rg;
        *(bf16x8*)(dst)     = a;
        *(bf16x8*)(dst + 8) = b;
    }
}

// ---------------------------------------------------------------------------
// GEMM, B^T layout: C[m][n] = sum_k A[m*K+k] * B[n*K+k]
// 128x128 tile, BK=64, 256 threads (4 waves, 2x2 of 64x64).
// DOUBLE-BUFFERED: stage tile k+1 via global_load_lds while computing tile k;
// ONE barrier per iteration (m97-ladder structure). XOR-swizzled source
// granule + swizzled ds_read_b128 -> conflict-free LDS.
// cols < qcols get scaled by qscale in the epilogue (Q pre-scale for attn).
// ---------------------------------------------------------------------------
template <bool OUT_BF16>
__global__ __launch_bounds__(256) void gemm_bt_kernel(const __bf16* __restrict__ A,
                                                      const __bf16* __restrict__ Bm,
                                                      float* __restrict__ Cf,
                                                      __bf16* __restrict__ Cb,
                                                      int N, int K, int qcols, float qscale)
{
    __shared__ __align__(16) __bf16 As[2][128 * 64];
    __shared__ __align__(16) __bf16 Bs[2][128 * 64];

    const int tid = threadIdx.x;
    const int l   = tid & 63;
    const int w   = tid >> 6;
    const int wr  = w >> 1, wc = w & 1;
    const int lo  = l & 15, hi = l >> 4;
    const int m0  = blockIdx.x * 128;
    const int n0  = blockIdx.y * 128;

    f32x4 acc[4][4] = {};

    // prologue: stage k-tile 0 -> buf 0
#pragma unroll
    for (int i = 0; i < 4; ++i) {
        int s   = i * 256 + tid;
        int row = s >> 3;
        int gg  = (s & 7) ^ (row & 7);
        __builtin_amdgcn_global_load_lds(AS1(A  + (size_t)(m0 + row) * K + gg * 8),
                                         AS3((char*)As[0] + s * 16), 16, 0, 0);
        __builtin_amdgcn_global_load_lds(AS1(Bm + (size_t)(n0 + row) * K + gg * 8),
                                         AS3((char*)Bs[0] + s * 16), 16, 0, 0);
    }
    __syncthreads();

    int cur = 0;
    for (int kk = 0; kk < K; kk += 64) {
        // stage next k-tile into buf cur^1 (overlaps with compute below)
        if (kk + 64 < K) {
#pragma unroll
            for (int i = 0; i < 4; ++i) {
                int s   = i * 256 + tid;
                int row = s >> 3;
                int gg  = (s & 7) ^ (row & 7);
                __builtin_amdgcn_global_load_lds(AS1(A  + (size_t)(m0 + row) * K + kk + 64 + gg * 8),
                                                 AS3((char*)As[cur ^ 1] + s * 16), 16, 0, 0);
                __builtin_amdgcn_global_load_lds(AS1(Bm + (size_t)(n0 + row) * K + kk + 64 + gg * 8),
                                                 AS3((char*)Bs[cur ^ 1] + s * 16), 16, 0, 0);
            }
        }

        __builtin_amdgcn_s_setprio(1);
#pragma unroll
        for (int ks = 0; ks < 2; ++ks) {
            bf16x8 af[4], bfr[4];
#pragma unroll
            for (int m = 0; m < 4; ++m) {
                int row = wr * 64 + m * 16 + lo;
                int gl  = (ks * 4 + hi) ^ (row & 7);
                af[m] = *(const bf16x8*)((const char*)As[cur] + row * 128 + gl * 16);
            }
#pragma unroll
            for (int n = 0; n < 4; ++n) {
                int row = wc * 64 + n * 16 + lo;
                int gl  = (ks * 4 + hi) ^ (row & 7);
                bfr[n] = *(const bf16x8*)((const char*)Bs[cur] + row * 128 + gl * 16);
            }
#pragma unroll
            for (int m = 0; m < 4; ++m)
#pragma unroll
                for (int n = 0; n < 4; ++n)
                    acc[m][n] = __builtin_amdgcn_mfma_f32_16x16x32_bf16(af[m], bfr[n], acc[m][n], 0, 0, 0);
        }
        __builtin_amdgcn_s_setprio(0);

        __syncthreads();   // next tile fully staged; cur buffer free for reuse
        cur ^= 1;
    }

#pragma unroll
    for (int m = 0; m < 4; ++m)
#pragma unroll
        for (int n = 0; n < 4; ++n)
#pragma unroll
            for (int r = 0; r < 4; ++r) {
                int row = m0 + wr * 64 + m * 16 + hi * 4 + r;
                int col = n0 + wc * 64 + n * 16 + lo;
                float v = acc[m][n][r];
                if (col < qcols) v *= qscale;
                if (OUT_BF16) Cb[(size_t)row * N + col] = (__bf16)v;
                else          Cf[(size_t)row * N + col] = v;
            }
}

// ---------------------------------------------------------------------------
// Flash attention chunk kernel (R8-measured config), 128-row q-tiles.
// Grid: 768 blocks x 256 threads (4 waves x 32 q-rows). ord = bid>>5 indexes
// (qt, chunk) table sorted longest-first; bh = bid&31 (same bh -> same XCD).
// qt<=7 direct; qt>=8 two chunks write f32 partial O (pO = dead d_out) +
// per-row (m,l) stats; attn_merge_kernel combines.
// ---------------------------------------------------------------------------
__global__ __launch_bounds__(256) void attn_chunk_kernel(const __bf16* __restrict__ qkv,
                                                         const __bf16* __restrict__ vT,
                                                         __bf16* __restrict__ att,
                                                         float* __restrict__ pO,
                                                         float* __restrict__ stats)
{
    // (qt, chunk) dispatch table, longest first. CC==255 -> direct.
    constexpr uint8_t QT[24] = { 8, 9,10,11,12,13,14,15,
                                15, 7,14, 6,13, 5,12, 4,
                                11, 3,10, 2, 9, 1, 8, 0};
    constexpr uint8_t CC[24] = { 0, 0, 0, 0, 0, 0, 0, 0,
                                 1,255, 1,255, 1,255, 1,255,
                                 1,255, 1,255, 1,255, 1,255};

    __shared__ __align__(16) __bf16 Ks[2][64 * 64];
    __shared__ __align__(16) __bf16 Vs[2][64 * 64];

    const int tid = threadIdx.x;
    const int l   = tid & 63;
    const int w   = tid >> 6;          // wave: 0..3
    const int lo5 = l & 31, hi5 = l >> 5;

    const int bid = blockIdx.x;
    const int ord = bid >> 5;
    const int bh  = bid & 31;
    const int h   = bh & 15;
    const int b   = bh >> 4;

    const int  qt     = QT[ord];
    const int  cc     = CC[ord];
    const bool direct = (cc == 255);
    const int  ntall  = 2 * qt + 2;
    const int  t0     = direct ? 0 : cc * 16;
    const int  t1     = direct ? ntall : min(cc * 16 + 16, ntall);
    const int  qb0    = qt * 128;

    const __bf16* Kbase = qkv + (size_t)b * Tq * 3072 + 1024 + h * 64;   // +k*3072 + d
    const __bf16* Vbase = vT  + (size_t)h * 64 * Mrows + b * Tq;         // +d*4096 + k

    // ones fragment for MFMA row-sum
    bf16x8 onesf;
#pragma unroll
    for (int jj = 0; jj < 8; ++jj) onesf[jj] = (__bf16)1.0f;

    // per-lane q row (global within sequence)
    const int qg = qb0 + w * 32 + lo5;

    // Q fragments (B-operand: col=q=lane&31, k(d) = ds*16 + hi5*8 + jj)
    bf16x8 qf[4];
    {
        const __bf16* Qp = qkv + (size_t)(b * Tq + qg) * 3072 + h * 64 + hi5 * 8;
#pragma unroll
        for (int ds = 0; ds < 4; ++ds) qf[ds] = *(const bf16x8*)(Qp + ds * 16);
    }

    f32x16 o0 = {}, o1 = {}, ls = {};
    float m = -1e30f;

    // prologue: stage tile t0 -> buf 0  (512 granules, 2 per thread)
#pragma unroll
    for (int i = 0; i < 2; ++i) {
        int s = i * 256 + tid;
        int row = s >> 3, gg = (s & 7) ^ (row & 7);
        __builtin_amdgcn_global_load_lds(AS1(Kbase + (size_t)(t0 * 64 + row) * 3072 + gg * 8),
                                         AS3((char*)Ks[0] + s * 16), 16, 0, 0);
        __builtin_amdgcn_global_load_lds(AS1(Vbase + (size_t)row * Mrows + t0 * 64 + gg * 8),
                                         AS3((char*)Vs[0] + s * 16), 16, 0, 0);
    }
    __syncthreads();

    int cur = 0;
    for (int t = t0; t < t1; ++t) {
        // stage next tile into buf cur^1 (overlaps with compute below)
        if (t + 1 < t1) {
            const int kn = (t + 1) * 64;
#pragma unroll
            for (int i = 0; i < 2; ++i) {
                int s = i * 256 + tid;
                int row = s >> 3, gg = (s & 7) ^ (row & 7);
                __builtin_amdgcn_global_load_lds(AS1(Kbase + (size_t)(kn + row) * 3072 + gg * 8),
                                                 AS3((char*)Ks[cur ^ 1] + s * 16), 16, 0, 0);
                __builtin_amdgcn_global_load_lds(AS1(Vbase + (size_t)row * Mrows + kn + gg * 8),
                                                 AS3((char*)Vs[cur ^ 1] + s * 16), 16, 0, 0);
            }
        }

        // --- S^T = K Q^T (swapped): lane holds S for q=lo5,
        //     k(r) = t*64 + (r&3)+8*(r>>2)+4*hi5 (sf0: +0, sf1: +32) ---
        f32x16 sf0 = {}, sf1 = {};
        __builtin_amdgcn_s_setprio(1);
#pragma unroll
        for (int ds = 0; ds < 4; ++ds) {
            {
                int row = lo5;
                int gl  = (ds * 2 + hi5) ^ (row & 7);
                bf16x8 kf = *(const bf16x8*)((const char*)Ks[cur] + row * 128 + gl * 16);
                sf0 = __builtin_amdgcn_mfma_f32_32x32x16_bf16(kf, qf[ds], sf0, 0, 0, 0);
            }
            {
                int row = 32 + lo5;
                int gl  = (ds * 2 + hi5) ^ (row & 7);
                bf16x8 kf = *(const bf16x8*)((const char*)Ks[cur] + row * 128 + gl * 16);
                sf1 = __builtin_amdgcn_mfma_f32_32x32x16_bf16(kf, qf[ds], sf1, 0, 0, 0);
            }
        }
        __builtin_amdgcn_s_setprio(0);

        // --- causal mask (only tiles that can cross this wave's diagonal) ---
        if (t * 64 + 63 > qb0 + w * 32) {
#pragma unroll
            for (int r = 0; r < 16; ++r) {
                int kcg = t * 64 + (r & 3) + 8 * (r >> 2) + 4 * hi5;
                if (kcg      > qg) sf0[r] = -1e30f;
                if (kcg + 32 > qg) sf1[r] = -1e30f;
            }
        }

        // --- row max: max3-friendly tree + one cross-half swap ---
        float t0m = fmaxf(sf0[0],  fmaxf(sf0[1],  sf0[2]));
        float t1m = fmaxf(sf0[3],  fmaxf(sf0[4],  sf0[5]));
        float t2m = fmaxf(sf0[6],  fmaxf(sf0[7],  sf0[8]));
        float t3m = fmaxf(sf0[9],  fmaxf(sf0[10], sf0[11]));
        float t4m = fmaxf(sf0[12], fmaxf(sf0[13], sf0[14]));
        float t5m = fmaxf(sf1[0],  fmaxf(sf1[1],  sf1[2]));
        float t6m = fmaxf(sf1[3],  fmaxf(sf1[4],  sf1[5]));
        float t7m = fmaxf(sf1[6],  fmaxf(sf1[7],  sf1[8]));
        float t8m = fmaxf(sf1[9],  fmaxf(sf1[10], sf1[11]));
        float t9m = fmaxf(sf1[12], fmaxf(sf1[13], sf1[14]));
        float u0 = fmaxf(t0m, fmaxf(t1m, t2m));
        float u1 = fmaxf(t3m, fmaxf(t4m, sf0[15]));
        float u2 = fmaxf(t5m, fmaxf(t6m, t7m));
        float u3 = fmaxf(t8m, fmaxf(t9m, sf1[15]));
        float pmh = fmaxf(fmaxf(u0, u1), fmaxf(u2, u3));
        float pm  = fmaxf(pmh, __shfl_xor(pmh, 32));

        // --- defer-max: rescale only on significant growth (THR=8 in log2) ---
        if (__any(pm > m + 8.0f)) {
            float mnew = fmaxf(m, pm);
            float fac  = __builtin_amdgcn_exp2f(m - mnew);
            m = mnew;
#pragma unroll
            for (int r = 0; r < 16; ++r) {
                int qreg = (r & 3) + 8 * (r >> 2) + 4 * hi5;
                float fr = __shfl(fac, qreg);
                o0[r] *= fr;
                o1[r] *= fr;
                ls[r] *= fr;
            }
        }

        // --- P = exp2(S - m), pack to bf16 words, exchange, PV + lsum MFMA ---
        __builtin_amdgcn_s_setprio(1);
#pragma unroll
        for (int kb = 0; kb < 2; ++kb) {
            uint32_t W[8];
#pragma unroll
            for (int wd = 0; wd < 8; ++wd) {
                float sa = (kb == 0) ? sf0[2 * wd]     : sf1[2 * wd];
                float sb = (kb == 0) ? sf0[2 * wd + 1] : sf1[2 * wd + 1];
                __bf16 ba = (__bf16)__builtin_amdgcn_exp2f(sa - m);
                __bf16 bb = (__bf16)__builtin_amdgcn_exp2f(sb - m);
                W[wd] = (uint32_t)__builtin_bit_cast(uint16_t, ba)
                      | ((uint32_t)__builtin_bit_cast(uint16_t, bb) << 16);
            }
            // cross-half word exchange (partner lane l^32 has same q)
            uint32_t Za = __shfl_xor(hi5 ? W[0] : W[2], 32);
            uint32_t Zb = __shfl_xor(hi5 ? W[1] : W[3], 32);
            uint32_t Zc = __shfl_xor(hi5 ? W[4] : W[6], 32);
            uint32_t Zd = __shfl_xor(hi5 ? W[5] : W[7], 32);

            {
                u32x4 fw = { hi5 ? Za : W[0], hi5 ? Zb : W[1],
                             hi5 ? W[2] : Za, hi5 ? W[3] : Zb };
                bf16x8 pa = __builtin_bit_cast(bf16x8, fw);
                const int kstep = kb * 2;
                {
                    int row = lo5;
                    int gl  = (kstep * 2 + hi5) ^ (row & 7);
                    bf16x8 vb = *(const bf16x8*)((const char*)Vs[cur] + row * 128 + gl * 16);
                    o0 = __builtin_amdgcn_mfma_f32_32x32x16_bf16(pa, vb, o0, 0, 0, 0);
                }
                {
                    int row = 32 + lo5;
                    int gl  = (kstep * 2 + hi5) ^ (row & 7);
                    bf16x8 vb = *(const bf16x8*)((const char*)Vs[cur] + row * 128 + gl * 16);
                    o1 = __builtin_amdgcn_mfma_f32_32x32x16_bf16(pa, vb, o1, 0, 0, 0);
                }
                ls = __builtin_amdgcn_mfma_f32_32x32x16_bf16(pa, onesf, ls, 0, 0, 0);
            }
            {
                u32x4 fw = { hi5 ? Zc : W[4], hi5 ? Zd : W[5],
                             hi5 ? W[6] : Zc, hi5 ? W[7] : Zd };
                bf16x8 pa = __builtin_bit_cast(bf16x8, fw);
                const int kstep = kb * 2 + 1;
                {
                    int row = lo5;
                    int gl  = (kstep * 2 + hi5) ^ (row & 7);
                    bf16x8 vb = *(const bf16x8*)((const char*)Vs[cur] + row * 128 + gl * 16);
                    o0 = __builtin_amdgcn_mfma_f32_32x32x16_bf16(pa, vb, o0, 0, 0, 0);
                }
                {
                    int row = 32 + lo5;
                    int gl  = (kstep * 2 + hi5) ^ (row & 7);
                    bf16x8 vb = *(const bf16x8*)((const char*)Vs[cur] + row * 128 + gl * 16);
                    o1 = __builtin_amdgcn_mfma_f32_32x32x16_bf16(pa, vb, o1, 0, 0, 0);
                }
                ls = __builtin_amdgcn_mfma_f32_32x32x16_bf16(pa, onesf, ls, 0, 0, 0);
            }
        }
        __builtin_amdgcn_s_setprio(0);

        __syncthreads();   // buf[cur^1] staged; protects buf reuse
        cur ^= 1;
    }

    if (direct) {
        // --- normalize + write att[4096][1024] ---
#pragma unroll
        for (int r = 0; r < 16; ++r) {
            float lr   = __builtin_amdgcn_rcpf(ls[r]);
            int   qreg = (r & 3) + 8 * (r >> 2) + 4 * hi5;
            int   rowg = b * Tq + qb0 + w * 32 + qreg;
            att[(size_t)rowg * Cd + h * 64 + lo5]      = (__bf16)(o0[r] * lr);
            att[(size_t)rowg * Cd + h * 64 + 32 + lo5] = (__bf16)(o1[r] * lr);
        }
    } else {
        // --- write unnormalized f32 partial + per-row (m, l) ---
        const int slot = bh * 16 + (qt - 8) * 2 + cc;   // 0..511
        float* po = pO + (size_t)slot * 8192;           // 128 rows x 64 d
#pragma unroll
        for (int r = 0; r < 16; ++r) {
            int   qreg = (r & 3) + 8 * (r >> 2) + 4 * hi5;
            int   row  = w * 32 + qreg;                 // 0..127
            po[row * 64 + lo5]      = o0[r];
            po[row * 64 + 32 + lo5] = o1[r];
            float mq = __shfl(m, qreg);
            if (lo5 == 0) {
                stats[(size_t)slot * 256 + row * 2 + 0] = mq;
                stats[(size_t)slot * 256 + row * 2 + 1] = ls[r];
            }
        }
    }
}

// ---------------------------------------------------------------------------
// Merge two KV-chunks: O = (w0*O0 + w1*O1) / (w0*l0 + w1*l1), w_c=exp2(m_c-M).
// Grid: 256 blocks (qt 8..15 x 32 bh) x 256 threads; 128 rows x 64 d each.
// ---------------------------------------------------------------------------
__global__ __launch_bounds__(256) void attn_merge_kernel(const float* __restrict__ pO,
                                                         const float* __restrict__ stats,
                                                         __bf16* __restrict__ att)
{
    const int mo  = blockIdx.x;
    const int bh  = mo & 31;
    const int qq  = mo >> 5;           // 0..7
    const int qt  = 8 + qq;
    const int h   = bh & 15;
    const int b   = bh >> 4;

    const int slot0 = bh * 16 + qq * 2;
    const int slot1 = slot0 + 1;

    const int tid = threadIdx.x;
    const int row = tid >> 1;          // 0..127
    const int c0  = (tid & 1) * 32;    // 0 or 32

    float m0 = stats[(size_t)slot0 * 256 + row * 2 + 0];
    float l0 = stats[(size_t)slot0 * 256 + row * 2 + 1];
    float m1 = stats[(size_t)slot1 * 256 + row * 2 + 0];
    float l1 = stats[(size_t)slot1 * 256 + row * 2 + 1];
    float M  = fmaxf(m0, m1);
    float w0 = __builtin_amdgcn_exp2f(m0 - M);
    float w1 = __builtin_amdgcn_exp2f(m1 - M);
    float inv = 1.0f / (w0 * l0 + w1 * l1);

    const float* p0 = pO + (size_t)slot0 * 8192 + row * 64 + c0;
    const float* p1 = pO + (size_t)slot1 * 8192 + row * 64 + c0;

    bf16x8 ov[4];
#pragma unroll
    for (int i = 0; i < 8; ++i) {
        f32x4 a  = ((const f32x4*)p0)[i];
        f32x4 bb = ((const f32x4*)p1)[i];
#pragma unroll
        for (int j = 0; j < 4; ++j)
            ov[i >> 1][(i & 1) * 4 + j] = (__bf16)((w0 * a[j] + w1 * bb[j]) * inv);
    }
    __bf16* dst = att + (size_t)(b * Tq + qt * 128 + row) * Cd + h * 64 + c0;
#pragma unroll
    for (int i = 0; i < 4; ++i) *(bf16x8*)(dst + i * 8) = ov[i];
}

// ---------------------------------------------------------------------------
// Launch
// ---------------------------------------------------------------------------
extern "C" void kernel_launch(void* const* d_in, const int* in_sizes, int n_in,
                              void* d_out, int out_size, void* d_ws, size_t ws_size,
                              hipStream_t stream)
{
    (void)in_sizes; (void)n_in; (void)out_size; (void)ws_size;

    const float* x    = (const float*)d_in[0];
    const float* Wqkv = (const float*)d_in[1];
    const float* Wo   = (const float*)d_in[2];
    float*       out  = (float*)d_out;

    char* ws = (char*)d_ws;
    __bf16* xb    = (__bf16*)(ws);                            //  8 MB: [4096][1024]
    __bf16* wqkvb = (__bf16*)(ws + (size_t)8  * 1024 * 1024); //  6 MB: [3072][1024]
    __bf16* wob   = (__bf16*)(ws + (size_t)14 * 1024 * 1024); //  2 MB: [1024][1024]
    __bf16* qkvb  = (__bf16*)(ws + (size_t)16 * 1024 * 1024); // 24 MB: [4096][3072]
    __bf16* attb  = (__bf16*)(ws + (size_t)40 * 1024 * 1024); //  8 MB: [4096][1024]
    __bf16* vTb   = xb;                                        // reuse: xb dead after gemm1
    float*  stats = (float*)wqkvb;                             // reuse: wqkvb dead after gemm1 (512 KB)
    float*  pO    = out;                                       // reuse: d_out dead until gemm2 (16 MB)

    cvt_bf16_kernel<<<2048, 256, 0, stream>>>(x,    xb,    Mrows * Cd / 8);
    cvt_bf16_kernel<<<1536, 256, 0, stream>>>(Wqkv, wqkvb, 3 * Cd * Cd / 8);
    cvt_bf16_kernel<<<512,  256, 0, stream>>>(Wo,   wob,   Cd * Cd / 8);

    dim3 g1(Mrows / 128, 3 * Cd / 128);   // 32 x 24
    gemm_bt_kernel<true><<<g1, 256, 0, stream>>>(xb, wqkvb, nullptr, qkvb, 3 * Cd, Cd,
                                                 1024, QSCALE);   // pre-scale Q columns

    dim3 gt(Mrows / 64, Cd / 64);         // 64 x 16
    transpose_v_kernel<<<gt, 256, 0, stream>>>(qkvb, vTb);

    attn_chunk_kernel<<<768, 256, 0, stream>>>(qkvb, vTb, attb, pO, stats);
    attn_merge_kernel<<<256, 256, 0, stream>>>(pO, stats, attb);

    dim3 g2(Mrows / 128, Cd / 128);       // 32 x 8
    gemm_bt_kernel<false><<<g2, 256, 0, stream>>>(attb, wob, out, nullptr, Cd, Cd,
                                                  0, 1.0f);
}

// Round 12
// 191.536 us; speedup vs baseline: 1.0337x; 1.0337x over previous
//
#include <hip/hip_runtime.h>
#include <hip/hip_bf16.h>
#include <stdint.h>
#include <stddef.h>

// ---------------------------------------------------------------------------
// CausalAttention: x[2,2048,1024] f32, W_QKV[3072,1024], W_O[1024,1024]
// qkv = x @ W_QKV^T ; per-head causal attention ; out = att @ W_O^T
// GEMMs: 128x128 tile, SINGLE-buffered m97 structure (dbuf regressed, m132).
// Attention: 256-row q-tiles (8 waves x 32 q-rows sharing K/V staging),
// swapped 32x32 QK^T, in-register softmax (exp2), split-KV chunks <=12
// k-tiles, normalized bf16 partials + L=m+log2(l) stats, weighted merge.
// ---------------------------------------------------------------------------

typedef __attribute__((ext_vector_type(8)))  __bf16   bf16x8;
typedef __attribute__((ext_vector_type(4)))  float    f32x4;
typedef __attribute__((ext_vector_type(16))) float    f32x16;
typedef __attribute__((ext_vector_type(4)))  uint32_t u32x4;

#define AS1(p) ((__attribute__((address_space(1))) void*)(p))
#define AS3(p) ((__attribute__((address_space(3))) void*)(p))

static constexpr int Tq    = 2048;
static constexpr int Cd    = 1024;
static constexpr int Mrows = 2 * Tq;   // 4096

// Q pre-scale: 1/sqrt(64) * log2(e)  (softmax runs in exp2 domain)
#define QSCALE 0.18033688011112042f

// ---------------------------------------------------------------------------
// f32 -> bf16 cast, vectorized 8/thread
// ---------------------------------------------------------------------------
__global__ __launch_bounds__(256) void cvt_bf16_kernel(const float* __restrict__ in,
                                                       __bf16* __restrict__ out, int n8)
{
    int idx    = blockIdx.x * blockDim.x + threadIdx.x;
    int stride = gridDim.x * blockDim.x;
    for (int i = idx; i < n8; i += stride) {
        f32x4 a = ((const f32x4*)in)[i * 2 + 0];
        f32x4 b = ((const f32x4*)in)[i * 2 + 1];
        bf16x8 o;
#pragma unroll
        for (int j = 0; j < 4; ++j) { o[j] = (__bf16)a[j]; o[4 + j] = (__bf16)b[j]; }
        ((bf16x8*)out)[i] = o;
    }
}

// ---------------------------------------------------------------------------
// V transpose: qkv V-part (cols 2048..3071) -> vT[1024][4096]
// ---------------------------------------------------------------------------
__global__ __launch_bounds__(256) void transpose_v_kernel(const __bf16* __restrict__ qkv,
                                                          __bf16* __restrict__ vT)
{
    __shared__ __bf16 tile[64][65];
    const int t   = threadIdx.x;
    const int r0  = blockIdx.x * 64;
    const int hd0 = blockIdx.y * 64;

    {
        const int rr = t >> 2, c16 = (t & 3) * 16;
        const __bf16* src = qkv + (size_t)(r0 + rr) * 3072 + 2048 + hd0 + c16;
        bf16x8 a = *(const bf16x8*)(src);
        bf16x8 b = *(const bf16x8*)(src + 8);
#pragma unroll
        for (int j = 0; j < 8; ++j) { tile[rr][c16 + j] = a[j]; tile[rr][c16 + 8 + j] = b[j]; }
    }
    __syncthreads();
    {
        const int hd_loc = t >> 2, rg = (t & 3) * 16;
        bf16x8 a, b;
#pragma unroll
        for (int j = 0; j < 8; ++j) { a[j] = tile[rg + j][hd_loc]; b[j] = tile[rg + 8 + j][hd_loc]; }
        __bf16* dst = vT + (size_t)(hd0 + hd_loc) * Mrows + r0 + rg;
        *(bf16x8*)(dst)     = a;
        *(bf16x8*)(dst + 8) = b;
    }
}

// ---------------------------------------------------------------------------
// GEMM, B^T layout: C[m][n] = sum_k A[m*K+k] * B[n*K+k]  (m97 structure,
// single-buffered 32 KB LDS — dbuf at 64 KB measured -11 us, m132 mechanism).
// cols < qcols get scaled by qscale in the epilogue (Q pre-scale for attn).
// ---------------------------------------------------------------------------
template <bool OUT_BF16>
__global__ __launch_bounds__(256) void gemm_bt_kernel(const __bf16* __restrict__ A,
                                                      const __bf16* __restrict__ Bm,
                                                      float* __restrict__ Cf,
                                                      __bf16* __restrict__ Cb,
                                                      int N, int K, int qcols, float qscale)
{
    __shared__ __align__(16) __bf16 As[128 * 64];
    __shared__ __align__(16) __bf16 Bs[128 * 64];

    const int tid = threadIdx.x;
    const int l   = tid & 63;
    const int w   = tid >> 6;
    const int wr  = w >> 1, wc = w & 1;
    const int lo  = l & 15, hi = l >> 4;
    const int m0  = blockIdx.x * 128;
    const int n0  = blockIdx.y * 128;

    f32x4 acc[4][4] = {};

    for (int kk = 0; kk < K; kk += 64) {
#pragma unroll
        for (int i = 0; i < 4; ++i) {
            int s   = i * 256 + tid;
            int row = s >> 3;
            int gg  = (s & 7) ^ (row & 7);
            const __bf16* srcA = A  + (size_t)(m0 + row) * K + kk + gg * 8;
            const __bf16* srcB = Bm + (size_t)(n0 + row) * K + kk + gg * 8;
            __builtin_amdgcn_global_load_lds(AS1(srcA), AS3((char*)As + s * 16), 16, 0, 0);
            __builtin_amdgcn_global_load_lds(AS1(srcB), AS3((char*)Bs + s * 16), 16, 0, 0);
        }
        __syncthreads();

#pragma unroll
        for (int ks = 0; ks < 2; ++ks) {
            bf16x8 af[4], bfr[4];
#pragma unroll
            for (int m = 0; m < 4; ++m) {
                int row = wr * 64 + m * 16 + lo;
                int gl  = (ks * 4 + hi) ^ (row & 7);
                af[m] = *(const bf16x8*)((const char*)As + row * 128 + gl * 16);
            }
#pragma unroll
            for (int n = 0; n < 4; ++n) {
                int row = wc * 64 + n * 16 + lo;
                int gl  = (ks * 4 + hi) ^ (row & 7);
                bfr[n] = *(const bf16x8*)((const char*)Bs + row * 128 + gl * 16);
            }
#pragma unroll
            for (int m = 0; m < 4; ++m)
#pragma unroll
                for (int n = 0; n < 4; ++n)
                    acc[m][n] = __builtin_amdgcn_mfma_f32_16x16x32_bf16(af[m], bfr[n], acc[m][n], 0, 0, 0);
        }
        __syncthreads();
    }

#pragma unroll
    for (int m = 0; m < 4; ++m)
#pragma unroll
        for (int n = 0; n < 4; ++n)
#pragma unroll
            for (int r = 0; r < 4; ++r) {
                int row = m0 + wr * 64 + m * 16 + hi * 4 + r;
                int col = n0 + wc * 64 + n * 16 + lo;
                float v = acc[m][n][r];
                if (col < qcols) v *= qscale;
                if (OUT_BF16) Cb[(size_t)row * N + col] = (__bf16)v;
                else          Cf[(size_t)row * N + col] = v;
            }
}

// ---------------------------------------------------------------------------
// Flash attention chunk kernel, 256-row q-tiles (8 waves x 32 q-rows).
// Grid: 480 blocks x 512 threads (<= 2 blocks/CU -> all co-resident).
// ord = bid>>5 indexes the (qt,t0,t1,slot) table sorted longest-first;
// bh = bid&31 (same bh -> same XCD L2 stream). qt in 0..7 (256-row tiles),
// k-tiles per qt = 4qt+4. qt0-2 direct; qt3-7 split into 2-3 chunks
// writing per-chunk NORMALIZED bf16 partials (pO = dead d_out, 32 KB/slot)
// + per-row L = m + log2(l); attn_merge_kernel combines.
// ---------------------------------------------------------------------------
__global__ __launch_bounds__(512) void attn_chunk_kernel(const __bf16* __restrict__ qkv,
                                                         const __bf16* __restrict__ vT,
                                                         __bf16* __restrict__ att,
                                                         __bf16* __restrict__ pO,
                                                         float* __restrict__ stats)
{
    // (qt, t0, t1, slot) table, longest chunks first. SL==255 -> direct.
    constexpr uint8_t QT[15] = { 5, 5, 2, 7, 7, 7, 6, 4, 4, 6, 6, 3, 3, 1, 0};
    constexpr uint8_t T0[15] = { 0,12, 0, 0,11,22, 0, 0,10,10,19, 0, 8, 0, 0};
    constexpr uint8_t T1[15] = {12,24,12,11,22,32,10,10,20,19,28, 8,16, 8, 4};
    constexpr uint8_t SL[15] = { 4, 5,255, 9,10,11, 6, 2, 3, 7, 8, 0, 1,255,255};

    __shared__ __align__(16) __bf16 Ks[2][64 * 64];
    __shared__ __align__(16) __bf16 Vs[2][64 * 64];

    const int tid = threadIdx.x;
    const int l   = tid & 63;
    const int w   = tid >> 6;          // wave: 0..7
    const int lo5 = l & 31, hi5 = l >> 5;

    const int bid = blockIdx.x;
    const int ord = bid >> 5;
    const int bh  = bid & 31;
    const int h   = bh & 15;
    const int b   = bh >> 4;

    const int  qt     = QT[ord];
    const int  sl     = SL[ord];
    const bool direct = (sl == 255);
    const int  t0     = T0[ord];
    const int  t1     = T1[ord];
    const int  qb0    = qt * 256;

    const __bf16* Kbase = qkv + (size_t)b * Tq * 3072 + 1024 + h * 64;   // +k*3072 + d
    const __bf16* Vbase = vT  + (size_t)h * 64 * Mrows + b * Tq;         // +d*4096 + k

    // ones fragment for MFMA row-sum
    bf16x8 onesf;
#pragma unroll
    for (int jj = 0; jj < 8; ++jj) onesf[jj] = (__bf16)1.0f;

    // per-lane q row (global within sequence)
    const int qg = qb0 + w * 32 + lo5;

    // Q fragments (B-operand: col=q=lane&31, k(d) = ds*16 + hi5*8 + jj)
    bf16x8 qf[4];
    {
        const __bf16* Qp = qkv + (size_t)(b * Tq + qg) * 3072 + h * 64 + hi5 * 8;
#pragma unroll
        for (int ds = 0; ds < 4; ++ds) qf[ds] = *(const bf16x8*)(Qp + ds * 16);
    }

    f32x16 o0 = {}, o1 = {}, ls = {};
    float m = -1e30f;

    // prologue: stage tile t0 -> buf 0 (512 granules K + 512 V, 1 each/thread)
    {
        int row = tid >> 3, gg = (tid & 7) ^ (row & 7);
        __builtin_amdgcn_global_load_lds(AS1(Kbase + (size_t)(t0 * 64 + row) * 3072 + gg * 8),
                                         AS3((char*)Ks[0] + tid * 16), 16, 0, 0);
        __builtin_amdgcn_global_load_lds(AS1(Vbase + (size_t)row * Mrows + t0 * 64 + gg * 8),
                                         AS3((char*)Vs[0] + tid * 16), 16, 0, 0);
    }
    __syncthreads();

    int cur = 0;
    for (int t = t0; t < t1; ++t) {
        // stage next tile into buf cur^1 (overlaps with compute below)
        if (t + 1 < t1) {
            const int kn = (t + 1) * 64;
            int row = tid >> 3, gg = (tid & 7) ^ (row & 7);
            __builtin_amdgcn_global_load_lds(AS1(Kbase + (size_t)(kn + row) * 3072 + gg * 8),
                                             AS3((char*)Ks[cur ^ 1] + tid * 16), 16, 0, 0);
            __builtin_amdgcn_global_load_lds(AS1(Vbase + (size_t)row * Mrows + kn + gg * 8),
                                             AS3((char*)Vs[cur ^ 1] + tid * 16), 16, 0, 0);
        }

        // --- S^T = K Q^T (swapped): lane holds S for q=lo5,
        //     k(r) = t*64 + (r&3)+8*(r>>2)+4*hi5 (sf0: +0, sf1: +32) ---
        f32x16 sf0 = {}, sf1 = {};
        __builtin_amdgcn_s_setprio(1);
#pragma unroll
        for (int ds = 0; ds < 4; ++ds) {
            {
                int row = lo5;
                int gl  = (ds * 2 + hi5) ^ (row & 7);
                bf16x8 kf = *(const bf16x8*)((const char*)Ks[cur] + row * 128 + gl * 16);
                sf0 = __builtin_amdgcn_mfma_f32_32x32x16_bf16(kf, qf[ds], sf0, 0, 0, 0);
            }
            {
                int row = 32 + lo5;
                int gl  = (ds * 2 + hi5) ^ (row & 7);
                bf16x8 kf = *(const bf16x8*)((const char*)Ks[cur] + row * 128 + gl * 16);
                sf1 = __builtin_amdgcn_mfma_f32_32x32x16_bf16(kf, qf[ds], sf1, 0, 0, 0);
            }
        }
        __builtin_amdgcn_s_setprio(0);

        // --- causal mask (only tiles that can cross this wave's diagonal) ---
        if (t * 64 + 63 > qb0 + w * 32) {
#pragma unroll
            for (int r = 0; r < 16; ++r) {
                int kcg = t * 64 + (r & 3) + 8 * (r >> 2) + 4 * hi5;
                if (kcg      > qg) sf0[r] = -1e30f;
                if (kcg + 32 > qg) sf1[r] = -1e30f;
            }
        }

        // --- row max: max3-friendly tree + one cross-half swap ---
        float t0m = fmaxf(sf0[0],  fmaxf(sf0[1],  sf0[2]));
        float t1m = fmaxf(sf0[3],  fmaxf(sf0[4],  sf0[5]));
        float t2m = fmaxf(sf0[6],  fmaxf(sf0[7],  sf0[8]));
        float t3m = fmaxf(sf0[9],  fmaxf(sf0[10], sf0[11]));
        float t4m = fmaxf(sf0[12], fmaxf(sf0[13], sf0[14]));
        float t5m = fmaxf(sf1[0],  fmaxf(sf1[1],  sf1[2]));
        float t6m = fmaxf(sf1[3],  fmaxf(sf1[4],  sf1[5]));
        float t7m = fmaxf(sf1[6],  fmaxf(sf1[7],  sf1[8]));
        float t8m = fmaxf(sf1[9],  fmaxf(sf1[10], sf1[11]));
        float t9m = fmaxf(sf1[12], fmaxf(sf1[13], sf1[14]));
        float u0 = fmaxf(t0m, fmaxf(t1m, t2m));
        float u1 = fmaxf(t3m, fmaxf(t4m, sf0[15]));
        float u2 = fmaxf(t5m, fmaxf(t6m, t7m));
        float u3 = fmaxf(t8m, fmaxf(t9m, sf1[15]));
        float pmh = fmaxf(fmaxf(u0, u1), fmaxf(u2, u3));
        float pm  = fmaxf(pmh, __shfl_xor(pmh, 32));

        // --- defer-max: rescale only on significant growth (THR=8 in log2) ---
        if (__any(pm > m + 8.0f)) {
            float mnew = fmaxf(m, pm);
            float fac  = __builtin_amdgcn_exp2f(m - mnew);
            m = mnew;
#pragma unroll
            for (int r = 0; r < 16; ++r) {
                int qreg = (r & 3) + 8 * (r >> 2) + 4 * hi5;
                float fr = __shfl(fac, qreg);
                o0[r] *= fr;
                o1[r] *= fr;
                ls[r] *= fr;
            }
        }

        // --- P = exp2(S - m), pack to bf16 words, exchange, PV + lsum MFMA ---
        __builtin_amdgcn_s_setprio(1);
#pragma unroll
        for (int kb = 0; kb < 2; ++kb) {
            uint32_t W[8];
#pragma unroll
            for (int wd = 0; wd < 8; ++wd) {
                float sa = (kb == 0) ? sf0[2 * wd]     : sf1[2 * wd];
                float sb = (kb == 0) ? sf0[2 * wd + 1] : sf1[2 * wd + 1];
                __bf16 ba = (__bf16)__builtin_amdgcn_exp2f(sa - m);
                __bf16 bb = (__bf16)__builtin_amdgcn_exp2f(sb - m);
                W[wd] = (uint32_t)__builtin_bit_cast(uint16_t, ba)
                      | ((uint32_t)__builtin_bit_cast(uint16_t, bb) << 16);
            }
            // cross-half word exchange (partner lane l^32 has same q)
            uint32_t Za = __shfl_xor(hi5 ? W[0] : W[2], 32);
            uint32_t Zb = __shfl_xor(hi5 ? W[1] : W[3], 32);
            uint32_t Zc = __shfl_xor(hi5 ? W[4] : W[6], 32);
            uint32_t Zd = __shfl_xor(hi5 ? W[5] : W[7], 32);

            {
                u32x4 fw = { hi5 ? Za : W[0], hi5 ? Zb : W[1],
                             hi5 ? W[2] : Za, hi5 ? W[3] : Zb };
                bf16x8 pa = __builtin_bit_cast(bf16x8, fw);
                const int kstep = kb * 2;
                {
                    int row = lo5;
                    int gl  = (kstep * 2 + hi5) ^ (row & 7);
                    bf16x8 vb = *(const bf16x8*)((const char*)Vs[cur] + row * 128 + gl * 16);
                    o0 = __builtin_amdgcn_mfma_f32_32x32x16_bf16(pa, vb, o0, 0, 0, 0);
                }
                {
                    int row = 32 + lo5;
                    int gl  = (kstep * 2 + hi5) ^ (row & 7);
                    bf16x8 vb = *(const bf16x8*)((const char*)Vs[cur] + row * 128 + gl * 16);
                    o1 = __builtin_amdgcn_mfma_f32_32x32x16_bf16(pa, vb, o1, 0, 0, 0);
                }
                ls = __builtin_amdgcn_mfma_f32_32x32x16_bf16(pa, onesf, ls, 0, 0, 0);
            }
            {
                u32x4 fw = { hi5 ? Zc : W[4], hi5 ? Zd : W[5],
                             hi5 ? W[6] : Zc, hi5 ? W[7] : Zd };
                bf16x8 pa = __builtin_bit_cast(bf16x8, fw);
                const int kstep = kb * 2 + 1;
                {
                    int row = lo5;
                    int gl  = (kstep * 2 + hi5) ^ (row & 7);
                    bf16x8 vb = *(const bf16x8*)((const char*)Vs[cur] + row * 128 + gl * 16);
                    o0 = __builtin_amdgcn_mfma_f32_32x32x16_bf16(pa, vb, o0, 0, 0, 0);
                }
                {
                    int row = 32 + lo5;
                    int gl  = (kstep * 2 + hi5) ^ (row & 7);
                    bf16x8 vb = *(const bf16x8*)((const char*)Vs[cur] + row * 128 + gl * 16);
                    o1 = __builtin_amdgcn_mfma_f32_32x32x16_bf16(pa, vb, o1, 0, 0, 0);
                }
                ls = __builtin_amdgcn_mfma_f32_32x32x16_bf16(pa, onesf, ls, 0, 0, 0);
            }
        }
        __builtin_amdgcn_s_setprio(0);

        __syncthreads();   // buf[cur^1] staged; protects buf reuse
        cur ^= 1;
    }

    if (direct) {
        // --- normalize + write att[4096][1024] ---
#pragma unroll
        for (int r = 0; r < 16; ++r) {
            float lr   = __builtin_amdgcn_rcpf(ls[r]);
            int   qreg = (r & 3) + 8 * (r >> 2) + 4 * hi5;
            int   rowg = b * Tq + qb0 + w * 32 + qreg;
            att[(size_t)rowg * Cd + h * 64 + lo5]      = (__bf16)(o0[r] * lr);
            att[(size_t)rowg * Cd + h * 64 + 32 + lo5] = (__bf16)(o1[r] * lr);
        }
    } else {
        // --- per-chunk normalized bf16 partial + L = m + log2(l) ---
        const int slot = bh * 12 + sl;                // 0..383
        __bf16* po = pO + (size_t)slot * 16384;       // 256 rows x 64 d (bf16)
#pragma unroll
        for (int r = 0; r < 16; ++r) {
            float lr   = __builtin_amdgcn_rcpf(ls[r]);
            int   qreg = (r & 3) + 8 * (r >> 2) + 4 * hi5;
            int   row  = w * 32 + qreg;               // 0..255
            po[row * 64 + lo5]      = (__bf16)(o0[r] * lr);
            po[row * 64 + 32 + lo5] = (__bf16)(o1[r] * lr);
            float mq = __shfl(m, qreg);
            if (lo5 == 0)
                stats[(size_t)slot * 256 + row] = mq + __builtin_amdgcn_logf(ls[r]);
        }
    }
}

// ---------------------------------------------------------------------------
// Merge 2-3 KV-chunks: O = sum_c w_c O_c with w_c = exp2(L_c - max L), renorm.
// Grid: 160 blocks (qt 3..7 x 32 bh) x 256 threads; 256 rows x 64 d each.
// ---------------------------------------------------------------------------
__global__ __launch_bounds__(256) void attn_merge_kernel(const __bf16* __restrict__ pO,
                                                         const float* __restrict__ stats,
                                                         __bf16* __restrict__ att)
{
    constexpr uint8_t BASE[5] = {0, 2, 4, 6, 9};

    const int mo  = blockIdx.x;
    const int bh  = mo & 31;
    const int qi  = mo >> 5;           // 0..4
    const int qt  = 3 + qi;
    const int h   = bh & 15;
    const int b   = bh >> 4;

    const int ncc   = (qt >= 6) ? 3 : 2;
    const int slot0 = bh * 12 + BASE[qi];

    const int row = threadIdx.x;       // 0..255

    float L0 = stats[(size_t)(slot0 + 0) * 256 + row];
    float L1 = stats[(size_t)(slot0 + 1) * 256 + row];
    float L2 = (ncc == 3) ? stats[(size_t)(slot0 + 2) * 256 + row] : -1e30f;
    float M  = fmaxf(L0, fmaxf(L1, L2));
    float w0 = __builtin_amdgcn_exp2f(L0 - M);
    float w1 = __builtin_amdgcn_exp2f(L1 - M);
    float w2 = (ncc == 3) ? __builtin_amdgcn_exp2f(L2 - M) : 0.0f;
    float inv = 1.0f / (w0 + w1 + w2);
    w0 *= inv; w1 *= inv; w2 *= inv;

    const __bf16* p0 = pO + (size_t)(slot0 + 0) * 16384 + row * 64;
    const __bf16* p1 = pO + (size_t)(slot0 + 1) * 16384 + row * 64;
    const __bf16* p2 = pO + (size_t)(slot0 + 2) * 16384 + row * 64;

    __bf16* dst = att + (size_t)(b * Tq + qt * 256 + row) * Cd + h * 64;
#pragma unroll
    for (int i = 0; i < 8; ++i) {
        bf16x8 a  = ((const bf16x8*)p0)[i];
        bf16x8 bb = ((const bf16x8*)p1)[i];
        bf16x8 ov;
        if (ncc == 3) {
            bf16x8 cc = ((const bf16x8*)p2)[i];
#pragma unroll
            for (int j = 0; j < 8; ++j)
                ov[j] = (__bf16)(w0 * (float)a[j] + w1 * (float)bb[j] + w2 * (float)cc[j]);
        } else {
#pragma unroll
            for (int j = 0; j < 8; ++j)
                ov[j] = (__bf16)(w0 * (float)a[j] + w1 * (float)bb[j]);
        }
        ((bf16x8*)dst)[i] = ov;
    }
}

// ---------------------------------------------------------------------------
// Launch
// ---------------------------------------------------------------------------
extern "C" void kernel_launch(void* const* d_in, const int* in_sizes, int n_in,
                              void* d_out, int out_size, void* d_ws, size_t ws_size,
                              hipStream_t stream)
{
    (void)in_sizes; (void)n_in; (void)out_size; (void)ws_size;

    const float* x    = (const float*)d_in[0];
    const float* Wqkv = (const float*)d_in[1];
    const float* Wo   = (const float*)d_in[2];
    float*       out  = (float*)d_out;

    char* ws = (char*)d_ws;
    __bf16* xb    = (__bf16*)(ws);                            //  8 MB: [4096][1024]
    __bf16* wqkvb = (__bf16*)(ws + (size_t)8  * 1024 * 1024); //  6 MB: [3072][1024]
    __bf16* wob   = (__bf16*)(ws + (size_t)14 * 1024 * 1024); //  2 MB: [1024][1024]
    __bf16* qkvb  = (__bf16*)(ws + (size_t)16 * 1024 * 1024); // 24 MB: [4096][3072]
    __bf16* attb  = (__bf16*)(ws + (size_t)40 * 1024 * 1024); //  8 MB: [4096][1024]
    __bf16* vTb   = xb;                                        // reuse: xb dead after gemm1
    float*  stats = (float*)wqkvb;                             // reuse: wqkvb dead after gemm1 (384 KB)
    __bf16* pO    = (__bf16*)out;                              // reuse: d_out dead until gemm2 (12 MB)

    cvt_bf16_kernel<<<2048, 256, 0, stream>>>(x,    xb,    Mrows * Cd / 8);
    cvt_bf16_kernel<<<1536, 256, 0, stream>>>(Wqkv, wqkvb, 3 * Cd * Cd / 8);
    cvt_bf16_kernel<<<512,  256, 0, stream>>>(Wo,   wob,   Cd * Cd / 8);

    dim3 g1(Mrows / 128, 3 * Cd / 128);   // 32 x 24
    gemm_bt_kernel<true><<<g1, 256, 0, stream>>>(xb, wqkvb, nullptr, qkvb, 3 * Cd, Cd,
                                                 1024, QSCALE);   // pre-scale Q columns

    dim3 gt(Mrows / 64, Cd / 64);         // 64 x 16
    transpose_v_kernel<<<gt, 256, 0, stream>>>(qkvb, vTb);

    attn_chunk_kernel<<<480, 512, 0, stream>>>(qkvb, vTb, attb, pO, stats);
    attn_merge_kernel<<<160, 256, 0, stream>>>(pO, stats, attb);

    dim3 g2(Mrows / 128, Cd / 128);       // 32 x 8
    gemm_bt_kernel<false><<<g2, 256, 0, stream>>>(attb, wob, out, nullptr, Cd, Cd,
                                                  0, 1.0f);
}